// Round 10
// baseline (169.681 us; speedup 1.0000x reference)
//
#include <hip/hip_runtime.h>
#include <hip/hip_bf16.h>
#include <math.h>
#include <stdint.h>

#define B_DIM 2
#define S_DIM 2048
#define E_DIM 768
#define H_DIM 8
#define D_DIM 96
#define M_DIM (B_DIM*S_DIM)          // 4096
#define SCALE_F 0.10206207261596575f // 96^-0.5
#define LOG2E_F 1.44269504088896341f

typedef _Float16 f16x8 __attribute__((ext_vector_type(8)));
typedef float    f32x4  __attribute__((ext_vector_type(4)));
typedef float    f32x16 __attribute__((ext_vector_type(16)));
typedef unsigned int u32x4 __attribute__((ext_vector_type(4)));

#define MFMA16H(a,b,c) __builtin_amdgcn_mfma_f32_16x16x32_f16(a,b,c,0,0,0)
#define MFMA32H(a,b,c) __builtin_amdgcn_mfma_f32_32x32x16_f16(a,b,c,0,0,0)

__device__ inline unsigned short f2h(float f) {
    return __builtin_bit_cast(unsigned short, (_Float16)f);
}

// pack two f32 -> one u32 of 2 f16 (v_cvt_pkrtz_f16_f32)
__device__ inline unsigned pk2(float a, float b) {
    return __builtin_bit_cast(unsigned, __builtin_amdgcn_cvt_pkrtz(a, b));
}

// CK-style async global->LDS, 16B per lane.
__device__ inline void gload16(const void* g, void* l) {
    auto gp = reinterpret_cast<const __attribute__((address_space(1))) uint32_t*>(
        reinterpret_cast<uintptr_t>(g));
    auto lp = reinterpret_cast<__attribute__((address_space(3))) uint32_t*>(
        reinterpret_cast<uintptr_t>(l));
    __builtin_amdgcn_global_load_lds(gp, lp, 16, 0, 0);
}

// ---------------------------------------------------------------------------
// Fused preprocessing, ONE launch:
//   blocks [0, 3072):   x [4096,768] fp32 -> fp16
//   blocks [3072, 3504): W{q,k,o} fp32 [k][n] -> W^T fp16 [n][k], 64x64 tiles
// Wq is pre-scaled by log2(e) so attention softmax runs in exp2 domain.
// ---------------------------------------------------------------------------
__global__ __launch_bounds__(256) void prep_kernel(
    const float* __restrict__ X,
    const float* __restrict__ W0, const float* __restrict__ W1,
    const float* __restrict__ W2,
    unsigned short* __restrict__ Xf,
    unsigned short* __restrict__ T0, unsigned short* __restrict__ T1,
    unsigned short* __restrict__ T2)
{
    const int tid = threadIdx.x;
    if (blockIdx.x < 3072) {
        int i = (blockIdx.x * 256 + tid) * 4;
        float4 v = *(const float4*)(X + i);
        ushort4 h;
        h.x = f2h(v.x); h.y = f2h(v.y); h.z = f2h(v.z); h.w = f2h(v.w);
        *(ushort4*)(Xf + i) = h;
        return;
    }
    int idx = blockIdx.x - 3072;        // 0..431
    int z = idx / 144, rem = idx % 144;
    const float* W; unsigned short* T;
    if (z == 0)      { W = W0; T = T0; }
    else if (z == 1) { W = W1; T = T1; }
    else             { W = W2; T = T2; }
    const float sc = (z == 0) ? LOG2E_F : 1.0f;   // log2e folded into Wq
    int k0 = (rem / 12) << 6, n0 = (rem % 12) << 6;

    __shared__ float tile[64][65];
    const int r = tid >> 4, c4 = (tid & 15) << 2;
    #pragma unroll
    for (int i = 0; i < 4; ++i) {
        float4 v = *(const float4*)(W + (size_t)(k0 + r + i*16)*E_DIM + n0 + c4);
        tile[r + i*16][c4+0] = v.x; tile[r + i*16][c4+1] = v.y;
        tile[r + i*16][c4+2] = v.z; tile[r + i*16][c4+3] = v.w;
    }
    __syncthreads();
    #pragma unroll
    for (int i = 0; i < 4; ++i) {
        int n = r + i*16;
        ushort4 h;
        h.x = f2h(tile[c4+0][n] * sc); h.y = f2h(tile[c4+1][n] * sc);
        h.z = f2h(tile[c4+2][n] * sc); h.w = f2h(tile[c4+3][n] * sc);
        *(ushort4*)(T + (size_t)(n0 + n)*E_DIM + k0 + c4) = h;
    }
}

// ---------------------------------------------------------------------------
// Fused Q/K projection fp16: 128x64 tile, 768 blocks, XCD swizzle.
// R24-proven minimal 2-phase pipeline: LDS double-buffered, issue next-tile
// gload16 before MFMA(cur), one barrier per K-step.
// ---------------------------------------------------------------------------
__global__ __launch_bounds__(256) void gemm_qk_kernel(
    const unsigned short* __restrict__ A, const unsigned short* __restrict__ Bt,
    const float* __restrict__ bq, const float* __restrict__ bk,
    unsigned short* __restrict__ Qf, unsigned short* __restrict__ Kf)
{
    __shared__ unsigned short sA[2*8192];   // [buf][panel][m][k32]
    __shared__ unsigned short sB[2*4096];   // [buf][panel][n][k32]

    const int tid  = threadIdx.x;
    const int lane = tid & 63;
    const int w    = tid >> 6;
    const int qn   = lane & 15, quad = lane >> 4;
    const int wm   = w & 1, wn = w >> 1;

    const int flat = blockIdx.x;            // 0..767
    const int g = flat & 7, s = flat >> 3;  // s: 0..95
    const int row0 = ((g << 2) + (s & 3)) << 7;   // 32 row-panels of 128
    const int col0 = (s >> 2) << 6;               // 24 col-tiles of 64

    const int ar = tid >> 2;            // 0..63
    const int ak = (tid & 3) << 3;      // 0,8,16,24

    const unsigned short* gA = A  + (size_t)(row0 + ar)*E_DIM + ak;
    const unsigned short* gB = Bt + (size_t)(col0 + ar)*E_DIM + ak;

    f32x4 acc[4][2];
    #pragma unroll
    for (int mt = 0; mt < 4; ++mt)
        #pragma unroll
        for (int nt = 0; nt < 2; ++nt)
            { acc[mt][nt][0]=0.f; acc[mt][nt][1]=0.f; acc[mt][nt][2]=0.f; acc[mt][nt][3]=0.f; }

    // prologue: stage tile 0 into buf 0
    gload16(gA,                 sA + tid*8);
    gload16(gA + 64*E_DIM,      sA + 2048 + tid*8);
    gload16(gA + 32,            sA + 4096 + tid*8);
    gload16(gA + 64*E_DIM + 32, sA + 6144 + tid*8);
    gload16(gB,                 sB + tid*8);
    gload16(gB + 32,            sB + 2048 + tid*8);
    __syncthreads();

    for (int it = 0; it < 12; ++it) {
        const int cur = it & 1, nb = cur ^ 1;
        if (it < 11) {                       // issue next-tile loads (async)
            const int kn = (it + 1) << 6;
            gload16(gA + kn,                 sA + nb*8192 + tid*8);
            gload16(gA + 64*E_DIM + kn,      sA + nb*8192 + 2048 + tid*8);
            gload16(gA + kn + 32,            sA + nb*8192 + 4096 + tid*8);
            gload16(gA + 64*E_DIM + kn + 32, sA + nb*8192 + 6144 + tid*8);
            gload16(gB + kn,                 sB + nb*4096 + tid*8);
            gload16(gB + kn + 32,            sB + nb*4096 + 2048 + tid*8);
        }

        #pragma unroll
        for (int kk = 0; kk < 2; ++kk) {
            f16x8 af[4], bf[2];
            #pragma unroll
            for (int mt = 0; mt < 4; ++mt)
                af[mt] = *(const f16x8*)
                    &sA[cur*8192 + kk*4096 + (wm*64 + mt*16 + qn)*32 + quad*8];
            #pragma unroll
            for (int nt = 0; nt < 2; ++nt)
                bf[nt] = *(const f16x8*)
                    &sB[cur*4096 + kk*2048 + (wn*32 + nt*16 + qn)*32 + quad*8];
            #pragma unroll
            for (int mt = 0; mt < 4; ++mt)
                #pragma unroll
                for (int nt = 0; nt < 2; ++nt)
                    acc[mt][nt] = MFMA16H(af[mt], bf[nt], acc[mt][nt]);
        }
        __syncthreads();   // drains next-tile gload16 (vmcnt) + ds reads (lgkm)
    }

    #pragma unroll
    for (int nt = 0; nt < 2; ++nt) {
        int n = col0 + wn*32 + nt*16 + qn;
        bool isQ = n < E_DIM;
        float bias = isQ ? bq[n] * LOG2E_F : bk[n - E_DIM];
        unsigned short* op = isQ ? Qf : Kf;
        int nc = isQ ? n : n - E_DIM;
        #pragma unroll
        for (int mt = 0; mt < 4; ++mt)
            #pragma unroll
            for (int r = 0; r < 4; ++r) {
                int m = row0 + wm*64 + mt*16 + quad*4 + r;
                op[(size_t)m*E_DIM + nc] = f2h(acc[mt][nt][r] + bias);
            }
    }
}

// ---------------------------------------------------------------------------
// Flash attention. R25: T15 lag-1 pipeline. Per iteration the wave computes
// QK(kt) [MFMA] and softmax(kt-1) [VALU/trans] as INDEPENDENT work (S carried
// in registers one tile deep) -> the scheduler interleaves the two pipes,
// then PV(kt-1). PV reads buf[p^1], so an end-of-iteration barrier separates
// those reads from iteration kt+1's stage writes (2 barriers/kt — same count
// as the proven R19 structure). #pragma unroll 2 renames the sc<-sn hand-off
// away. setprio brackets the whole compute region (not just MFMA clusters)
// so the pair doesn't fence the interleave. Everything else R23/R24-proven:
// 256 thr / 4 waves, key-split x2, dbuf sKh/sKt, in-register P via
// cvt_pkrtz+permlane32_swap, exp2 domain, tree reductions, defer-rescale
// THR=10, normalized Ohat.
// ---------------------------------------------------------------------------
__global__ __launch_bounds__(256) void attn_mfma_kernel(
    const unsigned short* __restrict__ Qf, const unsigned short* __restrict__ Kf,
    unsigned short* __restrict__ O0, unsigned short* __restrict__ O1,
    float2* __restrict__ ml)
{
    __shared__ unsigned short sKh[2][64][104];  // [buf][key][d]
    __shared__ unsigned short sKt[2][96][72];   // [buf][e][key] (key-rotated)

    const int tid  = threadIdx.x;
    const int w    = tid >> 6;       // wave 0..3: q rows [w*32, w*32+32)
    const int lane = tid & 63;
    const int col  = lane & 31;      // q for state/S^T-n/PV-n; e for PV-A rows
    const int half = lane >> 5;      // k-half selector
    const int b    = blockIdx.z >> 1;
    const int kh   = blockIdx.z & 1; // key half
    const int h    = blockIdx.y;
    const int q0   = blockIdx.x << 7;
    const int key0 = kh << 10;       // 0 or 1024

    // Q B-frags: B[k=d][n=q], lane reads 8 contiguous d at row q=col.
    f16x8 qf[6];
    {
        const size_t ro = ((size_t)(b*S_DIM + q0 + w*32 + col))*E_DIM
                          + h*D_DIM + half*8;
        #pragma unroll
        for (int kc = 0; kc < 6; ++kc)
            qf[kc] = *(const f16x8*)(Qf + ro + kc*16);
    }

    f32x16 o[3];
    #pragma unroll
    for (int nt = 0; nt < 3; ++nt)
        #pragma unroll
        for (int r = 0; r < 16; ++r) o[nt][r] = 0.f;
    float m_i = -INFINITY, l_i = 0.f;

    // staging (threads 0-127): rows {2sp, 2sp+1}, d cols {dq*8+32j+t}
    const bool stager = tid < 128;
    const int st = tid & 127;
    const int sp = st >> 2;          // 0..31
    const int dq = st & 3;           // 0..3
    const int kp2 = ((sp + ((dq & 1) << 4)) & 31) << 1;  // swizzled key pos (shorts)

    uint4 r0[3], r1[3];
    if (stager) {
        const size_t g0 = ((size_t)(b*S_DIM + key0 + 2*sp))*E_DIM + h*D_DIM + dq*8;
        #pragma unroll
        for (int i = 0; i < 3; ++i) {
            r0[i] = *(const uint4*)(Kf + g0 + 32*i);
            r1[i] = *(const uint4*)(Kf + g0 + E_DIM + 32*i);
        }
    }

    const int kswz = ((col >> 3) & 1) << 2;   // sKt read group XOR

    f32x16 sc[2];   // carried S of tile kt-1 (lag-1 state)

    // ---- prologue (kt = 0): stage buf0, QK(tile 0) into sc ----
    if (stager) {
        #pragma unroll
        for (int i = 0; i < 3; ++i) {
            *(uint4*)&sKh[0][2*sp  ][dq*8 + 32*i] = r0[i];
            *(uint4*)&sKh[0][2*sp+1][dq*8 + 32*i] = r1[i];
        }
        const unsigned short* p0 = (const unsigned short*)r0;
        const unsigned short* p1 = (const unsigned short*)r1;
        #pragma unroll
        for (int c = 0; c < 24; ++c) {
            int d = dq*8 + ((c >> 3) << 5) + (c & 7);
            unsigned pk = (unsigned)p0[c] | ((unsigned)p1[c] << 16);
            *(unsigned*)&sKt[0][d][kp2] = pk;
        }
    }
    __syncthreads();
    if (stager) {      // prefetch tile 1
        const size_t g0 = ((size_t)(b*S_DIM + key0 + 64 + 2*sp))*E_DIM
                          + h*D_DIM + dq*8;
        #pragma unroll
        for (int i = 0; i < 3; ++i) {
            r0[i] = *(const uint4*)(Kf + g0 + 32*i);
            r1[i] = *(const uint4*)(Kf + g0 + E_DIM + 32*i);
        }
    }
    __builtin_amdgcn_s_setprio(1);
    #pragma unroll
    for (int mt = 0; mt < 2; ++mt) {
        f32x16 acc;
        #pragma unroll
        for (int r = 0; r < 16; ++r) acc[r] = 0.f;
        #pragma unroll
        for (int kc = 0; kc < 6; ++kc) {
            f16x8 ah = *(const f16x8*)&sKh[0][mt*32 + col][kc*16 + half*8];
            acc = MFMA32H(ah, qf[kc], acc);
        }
        sc[mt] = acc;
    }
    __builtin_amdgcn_s_setprio(0);
    __syncthreads();

    // ---- main loop: kt = 1..16; iteration kt does QK(kt) + softmax/PV(kt-1)
    #pragma unroll 2
    for (int kt = 1; kt <= 16; ++kt) {
        const int p = kt & 1;
        const bool has = (kt < 16);

        if (has && stager) {               // stage tile kt -> buf[p]
            #pragma unroll
            for (int i = 0; i < 3; ++i) {
                *(uint4*)&sKh[p][2*sp  ][dq*8 + 32*i] = r0[i];
                *(uint4*)&sKh[p][2*sp+1][dq*8 + 32*i] = r1[i];
            }
            const unsigned short* p0 = (const unsigned short*)r0;
            const unsigned short* p1 = (const unsigned short*)r1;
            #pragma unroll
            for (int c = 0; c < 24; ++c) {
                int d = dq*8 + ((c >> 3) << 5) + (c & 7);
                unsigned pk = (unsigned)p0[c] | ((unsigned)p1[c] << 16);
                *(unsigned*)&sKt[p][d][kp2] = pk;
            }
        }
        __syncthreads();                   // buf[p] visible

        if (stager && kt < 15) {           // prefetch tile kt+1
            const size_t g0 = ((size_t)(b*S_DIM + key0 + (kt+1)*64 + 2*sp))*E_DIM
                              + h*D_DIM + dq*8;
            #pragma unroll
            for (int i = 0; i < 3; ++i) {
                r0[i] = *(const uint4*)(Kf + g0 + 32*i);
                r1[i] = *(const uint4*)(Kf + g0 + E_DIM + 32*i);
            }
        }

        __builtin_amdgcn_s_setprio(1);

        // ---- QK(kt) -> sn (independent of softmax below; pipes interleave)
        f32x16 sn[2];
        if (has) {
            #pragma unroll
            for (int mt = 0; mt < 2; ++mt) {
                f32x16 acc;
                #pragma unroll
                for (int r = 0; r < 16; ++r) acc[r] = 0.f;
                #pragma unroll
                for (int kc = 0; kc < 6; ++kc) {
                    f16x8 ah = *(const f16x8*)&sKh[p][mt*32 + col][kc*16 + half*8];
                    acc = MFMA32H(ah, qf[kc], acc);
                }
                sn[mt] = acc;
            }
        }

        // ---- online softmax of tile kt-1 (sc), per-lane state (q = col) ----
        float t[8];
        #pragma unroll
        for (int r = 0; r < 8; ++r)
            t[r] = fmaxf(fmaxf(sc[0][r], sc[0][r+8]), fmaxf(sc[1][r], sc[1][r+8]));
        float mx = fmaxf(fmaxf(fmaxf(t[0], t[1]), fmaxf(t[2], t[3])),
                         fmaxf(fmaxf(t[4], t[5]), fmaxf(t[6], t[7])));
        mx = fmaxf(mx, __shfl_xor(mx, 32));

        // defer-rescale: only rescale when tile max grows past m_i + 10
        if (__any(mx > m_i + 10.0f)) {
            float m_new = fmaxf(m_i, mx);
            float alpha = __builtin_amdgcn_exp2f(m_i - m_new);
            l_i *= alpha;
            #pragma unroll
            for (int nt = 0; nt < 3; ++nt)
                #pragma unroll
                for (int r = 0; r < 16; ++r) o[nt][r] *= alpha;
            m_i = m_new;
        }

        // p = exp2(s - m_i)  (bounded by 2^10; PV accum is f32)
        #pragma unroll
        for (int mt = 0; mt < 2; ++mt)
            #pragma unroll
            for (int r = 0; r < 16; ++r)
                sc[mt][r] = __builtin_amdgcn_exp2f(sc[mt][r] - m_i);

        // psum: depth-5 tree
        float a[8];
        #pragma unroll
        for (int r = 0; r < 8; ++r)
            a[r] = (sc[0][r] + sc[0][r+8]) + (sc[1][r] + sc[1][r+8]);
        float ps = ((a[0]+a[1]) + (a[2]+a[3])) + ((a[4]+a[5]) + (a[6]+a[7]));
        ps += __shfl_xor(ps, 32);
        l_i = l_i + ps;

        // ---- PV(kt-1) swapped: O^T[e][q] += V^T·P^T, V from buf[p^1] ----
        #pragma unroll
        for (int kc = 0; kc < 4; ++kc) {
            const int mt = kc >> 1;
            const int g0 = (kc & 1) << 3;
            unsigned A0 = pk2(sc[mt][g0+0], sc[mt][g0+1]);
            unsigned A1 = pk2(sc[mt][g0+2], sc[mt][g0+3]);
            unsigned B0 = pk2(sc[mt][g0+4], sc[mt][g0+5]);
            unsigned B1 = pk2(sc[mt][g0+6], sc[mt][g0+7]);
            auto w0 = __builtin_amdgcn_permlane32_swap(A0, B0, false, false);
            auto w1 = __builtin_amdgcn_permlane32_swap(A1, B1, false, false);
            u32x4 pw;
            pw[0] = w0[0]; pw[1] = w1[0]; pw[2] = w0[1]; pw[3] = w1[1];
            f16x8 pb = __builtin_bit_cast(f16x8, pw);
            #pragma unroll
            for (int nt = 0; nt < 3; ++nt) {
                f16x8 va = *(const f16x8*)
                    &sKt[p^1][nt*32 + col][(((kc << 1) | half) ^ kswz) << 3];
                o[nt] = MFMA32H(va, pb, o[nt]);
            }
        }
        __builtin_amdgcn_s_setprio(0);

        // hand off S state (coalesced away by unroll-2 register renaming)
        if (has) { sc[0] = sn[0]; sc[1] = sn[1]; }

        __syncthreads();   // PV(kt-1) reads of buf[p^1] done before kt+1 stage
    }

    // ---- epilogue: NORMALIZED Ohat (fp16), lane owns row q = col ----
    float inv = 1.0f / l_i;
    unsigned short* Ob = (kh ? O1 : O0)
        + ((size_t)(b*S_DIM + q0 + w*32 + col))*E_DIM + h*D_DIM;
    #pragma unroll
    for (int nt = 0; nt < 3; ++nt)
        #pragma unroll
        for (int rg = 0; rg < 4; ++rg) {
            ushort4 pk;
            pk.x = f2h(o[nt][4*rg+0]*inv); pk.y = f2h(o[nt][4*rg+1]*inv);
            pk.z = f2h(o[nt][4*rg+2]*inv); pk.w = f2h(o[nt][4*rg+3]*inv);
            *(ushort4*)(Ob + nt*32 + 8*rg + 4*half) = pk;
        }
    if (lane < 32) {
        int q = q0 + w*32 + lane;
        ml[((size_t)(kh*B_DIM + b)*H_DIM + h)*S_DIM + q] = make_float2(m_i, l_i);
    }
}

// ---------------------------------------------------------------------------
// Merge scales from (m,l), log2 domain, NORMALIZED partials:
//   weight_j = l_j * 2^(m_j - mm);  s_j = weight_j * SCALE / sum(weight)
// ---------------------------------------------------------------------------
__device__ inline float2 mkscale(const float2* __restrict__ ml, int m, int h) {
    int b = m >> 11, q = m & (S_DIM - 1);
    float2 e0 = ml[((size_t)b*H_DIM + h)*S_DIM + q];
    float2 e1 = ml[((size_t)(B_DIM + b)*H_DIM + h)*S_DIM + q];
    float mm = fmaxf(e0.x, e1.x);
    float w0 = e0.y * __builtin_amdgcn_exp2f(e0.x - mm);
    float w1 = e1.y * __builtin_amdgcn_exp2f(e1.x - mm);
    float inv = SCALE_F / (w0 + w1);
    return make_float2(w0*inv, w1*inv);
}

// ---------------------------------------------------------------------------
// Output projection + fused 2-way partial-combine, BK=64, XCD swizzle.
// R24-proven minimal 2-phase pipeline: issue-early loads, use-late combine,
// one barrier per K-step.
// ---------------------------------------------------------------------------
__global__ __launch_bounds__(256) void gemm_out_kernel(
    const unsigned short* __restrict__ O0, const unsigned short* __restrict__ O1,
    const float2* __restrict__ ml, const unsigned short* __restrict__ Bt,
    const float* __restrict__ bo, float* __restrict__ out)
{
    __shared__ unsigned short sA[2*4096];   // [buf][panel][m][k32]
    __shared__ unsigned short sB[2*4096];

    const int tid  = threadIdx.x;
    const int lane = tid & 63;
    const int w    = tid >> 6;
    const int qn   = lane & 15, quad = lane >> 4;
    const int wm   = w & 1, wn = w >> 1;

    const int flat = blockIdx.x;            // 0..767
    const int g = flat & 7, s = flat >> 3;  // s: 0..95
    const int row0 = ((g << 3) + (s & 7)) << 6;   // 64 row-panels of 64
    const int col0 = (s >> 3) << 6;               // 12 col-tiles of 64

    const int ar = tid >> 2;            // 0..63
    const int ak = (tid & 3) << 3;      // 0,8,16,24

    const size_t r0o = (size_t)(row0 + ar)*E_DIM;
    const unsigned short* gB = Bt + (size_t)(col0 + ar)*E_DIM + ak;

    f32x4 acc[2][2];
    #pragma unroll
    for (int mt = 0; mt < 2; ++mt)
        #pragma unroll
        for (int nt = 0; nt < 2; ++nt)
            { acc[mt][nt][0]=0.f; acc[mt][nt][1]=0.f; acc[mt][nt][2]=0.f; acc[mt][nt][3]=0.f; }

    // tile-0 combine inputs + scales
    f16x8 uA = *(const f16x8*)(O0 + r0o + ak);
    f16x8 vA = *(const f16x8*)(O1 + r0o + ak);
    f16x8 uB = *(const f16x8*)(O0 + r0o + 32 + ak);
    f16x8 vB = *(const f16x8*)(O1 + r0o + 32 + ak);
    int hA = 0, hB = 0;                    // heads of panels (k<96 -> both 0)
    float2 s2 = mkscale(ml, row0 + ar, 0);
    _Float16 axA = (_Float16)s2.x, ayA = (_Float16)s2.y;
    _Float16 axB = axA, ayB = ayA;

    // prologue: stage tile 0 into buf 0
    {
        f16x8 c0 = uA * axA + vA * ayA;
        f16x8 c1 = uB * axB + vB * ayB;
        *(f16x8*)&sA[       ar*32 + ak] = c0;
        *(f16x8*)&sA[2048 + ar*32 + ak] = c1;
        gload16(gB,      sB + tid*8);
        gload16(gB + 32, sB + 2048 + tid*8);
    }
    __syncthreads();

    for (int it = 0; it < 12; ++it) {
        const int cur = it & 1, nb = cur ^ 1;
        const bool hasNext = it < 11;
        const int kn = (it + 1) << 6;

        if (hasNext) {                      // issue-early: next-tile loads
            gload16(gB + kn,      sB + nb*4096 + tid*8);
            gload16(gB + kn + 32, sB + nb*4096 + 2048 + tid*8);
            uA = *(const f16x8*)(O0 + r0o + kn + ak);
            vA = *(const f16x8*)(O1 + r0o + kn + ak);
            uB = *(const f16x8*)(O0 + r0o + kn + 32 + ak);
            vB = *(const f16x8*)(O1 + r0o + kn + 32 + ak);
        }

        #pragma unroll
        for (int kk = 0; kk < 2; ++kk) {
            f16x8 af[2], bf[2];
            #pragma unroll
            for (int mt = 0; mt < 2; ++mt)
                af[mt] = *(const f16x8*)
                    &sA[cur*4096 + kk*2048 + (wm*32 + mt*16 + qn)*32 + quad*8];
            #pragma unroll
            for (int nt = 0; nt < 2; ++nt)
                bf[nt] = *(const f16x8*)
                    &sB[cur*4096 + kk*2048 + (wn*32 + nt*16 + qn)*32 + quad*8];
            #pragma unroll
            for (int mt = 0; mt < 2; ++mt)
                #pragma unroll
                for (int nt = 0; nt < 2; ++nt)
                    acc[mt][nt] = MFMA16H(af[mt], bf[nt], acc[mt][nt]);
        }

        if (hasNext) {                      // use-late: combine + sA write
            int nhA = kn / D_DIM, nhB = (kn + 32) / D_DIM;
            if (nhA != hA) {
                float2 t = mkscale(ml, row0 + ar, nhA);
                axA = (_Float16)t.x; ayA = (_Float16)t.y; hA = nhA;
            }
            if (nhB != hB) {
                float2 t = mkscale(ml, row0 + ar, nhB);
                axB = (_Float16)t.x; ayB = (_Float16)t.y; hB = nhB;
            }
            f16x8 c0 = uA * axA + vA * ayA;
            f16x8 c1 = uB * axB + vB * ayB;
            *(f16x8*)&sA[nb*4096 +        ar*32 + ak] = c0;
            *(f16x8*)&sA[nb*4096 + 2048 + ar*32 + ak] = c1;
        }
        __syncthreads();   // drains gload16 (vmcnt) + ds ops (lgkm)
    }

    #pragma unroll
    for (int nt = 0; nt < 2; ++nt) {
        int n = col0 + wn*32 + nt*16 + qn;
        float bias = bo[n];
        #pragma unroll
        for (int mt = 0; mt < 2; ++mt)
            #pragma unroll
            for (int r = 0; r < 4; ++r) {
                int m = row0 + wm*32 + mt*16 + quad*4 + r;
                out[(size_t)m*E_DIM + n] = acc[mt][nt][r] + bias;
            }
    }
}

// ---------------------------------------------------------------------------
extern "C" void kernel_launch(void* const* d_in, const int* in_sizes, int n_in,
                              void* d_out, int out_size, void* d_ws, size_t ws_size,
                              hipStream_t stream)
{
    const float* x  = (const float*)d_in[0];
    const float* Wq = (const float*)d_in[1];
    const float* bq = (const float*)d_in[2];
    const float* Wk = (const float*)d_in[3];
    const float* bk = (const float*)d_in[4];
    const float* Wo = (const float*)d_in[5];
    const float* bo = (const float*)d_in[6];
    float* out = (float*)d_out;

    const size_t NE = (size_t)M_DIM * E_DIM;        // 3.1M elems
    const size_t WE = (size_t)E_DIM * E_DIM;        // 590K elems
    unsigned short* xf    = (unsigned short*)d_ws;  // NE (aliased Oh0 later)
    unsigned short* WqkT  = xf + NE;                // 2*WE  [Wq^T | Wk^T] fp16
    unsigned short* WoT   = WqkT + 2*WE;            // WE
    unsigned short* Qf    = WoT + WE;               // NE
    unsigned short* Kf    = Qf + NE;                // NE
    unsigned short* Oh1   = Kf + NE;                // NE
    float2*         mlbuf = (float2*)(Oh1 + NE);    // 2*B*H*S float2 = 512 KB
    unsigned short* Oh0   = xf;                     // alias: x dead after gemm_qk

    dim3 blk(256);
    hipLaunchKernelGGL(prep_kernel, dim3(3504), blk, 0, stream,
                       x, Wq, Wk, Wo, xf, WqkT, WqkT + WE, WoT);

    hipLaunchKernelGGL(gemm_qk_kernel, dim3(768), blk, 0, stream,
                       xf, WqkT, bq, bk, Qf, Kf);

    hipLaunchKernelGGL(attn_mfma_kernel, dim3(S_DIM/128, H_DIM, B_DIM*2), blk, 0,
                       stream, Qf, Kf, Oh0, Oh1, mlbuf);

    hipLaunchKernelGGL(gemm_out_kernel, dim3(768), blk, 0, stream,
                       Oh0, Oh1, mlbuf, WoT, bo, out);
}

// Round 11
// 150.599 us; speedup vs baseline: 1.1267x; 1.1267x over previous
//
#include <hip/hip_runtime.h>
#include <hip/hip_bf16.h>
#include <math.h>
#include <stdint.h>

#define B_DIM 2
#define S_DIM 2048
#define E_DIM 768
#define H_DIM 8
#define D_DIM 96
#define M_DIM (B_DIM*S_DIM)          // 4096
#define SCALE_F 0.10206207261596575f // 96^-0.5
#define LOG2E_F 1.44269504088896341f

typedef _Float16 f16x8 __attribute__((ext_vector_type(8)));
typedef float    f32x4  __attribute__((ext_vector_type(4)));
typedef float    f32x16 __attribute__((ext_vector_type(16)));
typedef unsigned int u32x4 __attribute__((ext_vector_type(4)));

#define MFMA16H(a,b,c) __builtin_amdgcn_mfma_f32_16x16x32_f16(a,b,c,0,0,0)
#define MFMA32H(a,b,c) __builtin_amdgcn_mfma_f32_32x32x16_f16(a,b,c,0,0,0)

__device__ inline unsigned short f2h(float f) {
    return __builtin_bit_cast(unsigned short, (_Float16)f);
}

// pack two f32 -> one u32 of 2 f16 (v_cvt_pkrtz_f16_f32)
__device__ inline unsigned pk2(float a, float b) {
    return __builtin_bit_cast(unsigned, __builtin_amdgcn_cvt_pkrtz(a, b));
}

// CK-style async global->LDS, 16B per lane.
__device__ inline void gload16(const void* g, void* l) {
    auto gp = reinterpret_cast<const __attribute__((address_space(1))) uint32_t*>(
        reinterpret_cast<uintptr_t>(g));
    auto lp = reinterpret_cast<__attribute__((address_space(3))) uint32_t*>(
        reinterpret_cast<uintptr_t>(l));
    __builtin_amdgcn_global_load_lds(gp, lp, 16, 0, 0);
}

// ---------------------------------------------------------------------------
// Fused preprocessing, ONE launch:
//   blocks [0, 3072):   x [4096,768] fp32 -> fp16
//   blocks [3072, 3504): W{q,k,o} fp32 [k][n] -> W^T fp16 [n][k], 64x64 tiles
// Wq is pre-scaled by log2(e) so attention softmax runs in exp2 domain.
// ---------------------------------------------------------------------------
__global__ __launch_bounds__(256) void prep_kernel(
    const float* __restrict__ X,
    const float* __restrict__ W0, const float* __restrict__ W1,
    const float* __restrict__ W2,
    unsigned short* __restrict__ Xf,
    unsigned short* __restrict__ T0, unsigned short* __restrict__ T1,
    unsigned short* __restrict__ T2)
{
    const int tid = threadIdx.x;
    if (blockIdx.x < 3072) {
        int i = (blockIdx.x * 256 + tid) * 4;
        float4 v = *(const float4*)(X + i);
        ushort4 h;
        h.x = f2h(v.x); h.y = f2h(v.y); h.z = f2h(v.z); h.w = f2h(v.w);
        *(ushort4*)(Xf + i) = h;
        return;
    }
    int idx = blockIdx.x - 3072;        // 0..431
    int z = idx / 144, rem = idx % 144;
    const float* W; unsigned short* T;
    if (z == 0)      { W = W0; T = T0; }
    else if (z == 1) { W = W1; T = T1; }
    else             { W = W2; T = T2; }
    const float sc = (z == 0) ? LOG2E_F : 1.0f;   // log2e folded into Wq
    int k0 = (rem / 12) << 6, n0 = (rem % 12) << 6;

    __shared__ float tile[64][65];
    const int r = tid >> 4, c4 = (tid & 15) << 2;
    #pragma unroll
    for (int i = 0; i < 4; ++i) {
        float4 v = *(const float4*)(W + (size_t)(k0 + r + i*16)*E_DIM + n0 + c4);
        tile[r + i*16][c4+0] = v.x; tile[r + i*16][c4+1] = v.y;
        tile[r + i*16][c4+2] = v.z; tile[r + i*16][c4+3] = v.w;
    }
    __syncthreads();
    #pragma unroll
    for (int i = 0; i < 4; ++i) {
        int n = r + i*16;
        ushort4 h;
        h.x = f2h(tile[c4+0][n] * sc); h.y = f2h(tile[c4+1][n] * sc);
        h.z = f2h(tile[c4+2][n] * sc); h.w = f2h(tile[c4+3][n] * sc);
        *(ushort4*)(T + (size_t)(n0 + n)*E_DIM + k0 + c4) = h;
    }
}

// ---------------------------------------------------------------------------
// Fused Q/K projection fp16. R26: 128x128 tile (R20's refcheck-passed
// mapping) + R24's 2-phase pipeline. 384 blocks (XCD-divisible), acc[4][4],
// 16 MFMA : 8 LDS-frag-loads per wave K-step (2x the 128x64 density),
// double-buffered LDS 64 KB, one barrier per K-step.
// ---------------------------------------------------------------------------
__global__ __launch_bounds__(256) void gemm_qk_kernel(
    const unsigned short* __restrict__ A, const unsigned short* __restrict__ Bt,
    const float* __restrict__ bq, const float* __restrict__ bk,
    unsigned short* __restrict__ Qf, unsigned short* __restrict__ Kf)
{
    __shared__ unsigned short sA[2*8192];   // [buf][panel][m][k32]
    __shared__ unsigned short sB[2*8192];   // [buf][panel][n][k32]

    const int tid  = threadIdx.x;
    const int lane = tid & 63;
    const int w    = tid >> 6;
    const int qn   = lane & 15, quad = lane >> 4;
    const int wm   = w & 1, wn = w >> 1;

    const int flat = blockIdx.x;            // 0..383
    const int g = flat & 7, s = flat >> 3;  // s: 0..47
    const int row0 = ((g << 2) + (s & 3)) << 7;   // 32 row-panels of 128
    const int col0 = (s >> 2) << 7;               // 12 col-tiles of 128

    const int ar = tid >> 2;            // 0..63
    const int ak = (tid & 3) << 3;      // 0,8,16,24

    const unsigned short* gA = A  + (size_t)(row0 + ar)*E_DIM + ak;
    const unsigned short* gB = Bt + (size_t)(col0 + ar)*E_DIM + ak;

    f32x4 acc[4][4];
    #pragma unroll
    for (int mt = 0; mt < 4; ++mt)
        #pragma unroll
        for (int nt = 0; nt < 4; ++nt)
            { acc[mt][nt][0]=0.f; acc[mt][nt][1]=0.f; acc[mt][nt][2]=0.f; acc[mt][nt][3]=0.f; }

    // prologue: stage tile 0 into buf 0
    gload16(gA,                 sA + tid*8);
    gload16(gA + 64*E_DIM,      sA + 2048 + tid*8);
    gload16(gA + 32,            sA + 4096 + tid*8);
    gload16(gA + 64*E_DIM + 32, sA + 6144 + tid*8);
    gload16(gB,                 sB + tid*8);
    gload16(gB + 64*E_DIM,      sB + 2048 + tid*8);
    gload16(gB + 32,            sB + 4096 + tid*8);
    gload16(gB + 64*E_DIM + 32, sB + 6144 + tid*8);
    __syncthreads();

    for (int it = 0; it < 12; ++it) {
        const int cur = it & 1, nb = cur ^ 1;
        if (it < 11) {                       // issue next-tile loads (async)
            const int kn = (it + 1) << 6;
            gload16(gA + kn,                 sA + nb*8192 + tid*8);
            gload16(gA + 64*E_DIM + kn,      sA + nb*8192 + 2048 + tid*8);
            gload16(gA + kn + 32,            sA + nb*8192 + 4096 + tid*8);
            gload16(gA + 64*E_DIM + kn + 32, sA + nb*8192 + 6144 + tid*8);
            gload16(gB + kn,                 sB + nb*8192 + tid*8);
            gload16(gB + 64*E_DIM + kn,      sB + nb*8192 + 2048 + tid*8);
            gload16(gB + kn + 32,            sB + nb*8192 + 4096 + tid*8);
            gload16(gB + 64*E_DIM + kn + 32, sB + nb*8192 + 6144 + tid*8);
        }

        #pragma unroll
        for (int kk = 0; kk < 2; ++kk) {
            f16x8 af[4], bf[4];
            #pragma unroll
            for (int mt = 0; mt < 4; ++mt)
                af[mt] = *(const f16x8*)
                    &sA[cur*8192 + kk*4096 + (wm*64 + mt*16 + qn)*32 + quad*8];
            #pragma unroll
            for (int nt = 0; nt < 4; ++nt)
                bf[nt] = *(const f16x8*)
                    &sB[cur*8192 + kk*4096 + (wn*64 + nt*16 + qn)*32 + quad*8];
            #pragma unroll
            for (int mt = 0; mt < 4; ++mt)
                #pragma unroll
                for (int nt = 0; nt < 4; ++nt)
                    acc[mt][nt] = MFMA16H(af[mt], bf[nt], acc[mt][nt]);
        }
        __syncthreads();   // drains next-tile gload16 (vmcnt) + ds reads (lgkm)
    }

    #pragma unroll
    for (int nt = 0; nt < 4; ++nt) {
        int n = col0 + wn*64 + nt*16 + qn;
        bool isQ = n < E_DIM;
        float bias = isQ ? bq[n] * LOG2E_F : bk[n - E_DIM];
        unsigned short* op = isQ ? Qf : Kf;
        int nc = isQ ? n : n - E_DIM;
        #pragma unroll
        for (int mt = 0; mt < 4; ++mt)
            #pragma unroll
            for (int r = 0; r < 4; ++r) {
                int m = row0 + wm*64 + mt*16 + quad*4 + r;
                op[(size_t)m*E_DIM + nc] = f2h(acc[mt][nt][r] + bias);
            }
    }
}

// ---------------------------------------------------------------------------
// Flash attention (R23-proven, 46.7-47.0 us — R25's lag-1 pipeline REVERTED:
// the extra barrier per kt cost +19 us at 2 blocks/CU). 256 thr / 4 waves,
// key-split x2, double-buffered sKh/sKt (ONE barrier per kt), in-register P
// (cvt_pkrtz + permlane32_swap), exp2 domain, tree reductions, defer-rescale
// THR=10, normalized Ohat, T5 s_setprio around MFMA clusters.
// ---------------------------------------------------------------------------
__global__ __launch_bounds__(256) void attn_mfma_kernel(
    const unsigned short* __restrict__ Qf, const unsigned short* __restrict__ Kf,
    unsigned short* __restrict__ O0, unsigned short* __restrict__ O1,
    float2* __restrict__ ml)
{
    __shared__ unsigned short sKh[2][64][104];  // [buf][key][d]
    __shared__ unsigned short sKt[2][96][72];   // [buf][e][key] (key-rotated)

    const int tid  = threadIdx.x;
    const int w    = tid >> 6;       // wave 0..3: q rows [w*32, w*32+32)
    const int lane = tid & 63;
    const int col  = lane & 31;      // q for state/S^T-n/PV-n; e for PV-A rows
    const int half = lane >> 5;      // k-half selector
    const int b    = blockIdx.z >> 1;
    const int kh   = blockIdx.z & 1; // key half
    const int h    = blockIdx.y;
    const int q0   = blockIdx.x << 7;
    const int key0 = kh << 10;       // 0 or 1024

    // Q B-frags: B[k=d][n=q], lane reads 8 contiguous d at row q=col.
    f16x8 qf[6];
    {
        const size_t ro = ((size_t)(b*S_DIM + q0 + w*32 + col))*E_DIM
                          + h*D_DIM + half*8;
        #pragma unroll
        for (int kc = 0; kc < 6; ++kc)
            qf[kc] = *(const f16x8*)(Qf + ro + kc*16);
    }

    f32x16 o[3];
    #pragma unroll
    for (int nt = 0; nt < 3; ++nt)
        #pragma unroll
        for (int r = 0; r < 16; ++r) o[nt][r] = 0.f;
    float m_i = -INFINITY, l_i = 0.f;

    // staging (threads 0-127): rows {2sp, 2sp+1}, d cols {dq*8+32j+t}
    const bool stager = tid < 128;
    const int st = tid & 127;
    const int sp = st >> 2;          // 0..31
    const int dq = st & 3;           // 0..3
    const int kp2 = ((sp + ((dq & 1) << 4)) & 31) << 1;  // swizzled key pos (shorts)

    uint4 r0[3], r1[3];
    if (stager) {
        const size_t g0 = ((size_t)(b*S_DIM + key0 + 2*sp))*E_DIM + h*D_DIM + dq*8;
        #pragma unroll
        for (int i = 0; i < 3; ++i) {
            r0[i] = *(const uint4*)(Kf + g0 + 32*i);
            r1[i] = *(const uint4*)(Kf + g0 + E_DIM + 32*i);
        }
    }

    const int kswz = ((col >> 3) & 1) << 2;   // sKt read group XOR

    for (int kt = 0; kt < 16; ++kt) {
        const int p = kt & 1;
        if (stager) {
            #pragma unroll
            for (int i = 0; i < 3; ++i) {
                *(uint4*)&sKh[p][2*sp  ][dq*8 + 32*i] = r0[i];
                *(uint4*)&sKh[p][2*sp+1][dq*8 + 32*i] = r1[i];
            }
            const unsigned short* p0 = (const unsigned short*)r0;
            const unsigned short* p1 = (const unsigned short*)r1;
            #pragma unroll
            for (int c = 0; c < 24; ++c) {
                int d = dq*8 + ((c >> 3) << 5) + (c & 7);
                unsigned pk = (unsigned)p0[c] | ((unsigned)p1[c] << 16);
                *(unsigned*)&sKt[p][d][kp2] = pk;
            }
        }
        __syncthreads();   // buf[p] visible; also fences buf[p] reads of kt-2

        // prefetch next tile (overlaps with compute below)
        if (stager && kt + 1 < 16) {
            const size_t g0 = ((size_t)(b*S_DIM + key0 + (kt+1)*64 + 2*sp))*E_DIM
                              + h*D_DIM + dq*8;
            #pragma unroll
            for (int i = 0; i < 3; ++i) {
                r0[i] = *(const uint4*)(Kf + g0 + 32*i);
                r1[i] = *(const uint4*)(Kf + g0 + E_DIM + 32*i);
            }
        }

        // ---- S^T = K·Q^T (fp16), D[m=key][n=q], log2 units ----
        f32x16 s[2];
        __builtin_amdgcn_s_setprio(1);                 // T5: favor MFMA wave
        #pragma unroll
        for (int mt = 0; mt < 2; ++mt) {
            f32x16 acc;
            #pragma unroll
            for (int r = 0; r < 16; ++r) acc[r] = 0.f;
            #pragma unroll
            for (int kc = 0; kc < 6; ++kc) {
                f16x8 ah = *(const f16x8*)&sKh[p][mt*32 + col][kc*16 + half*8];
                acc = MFMA32H(ah, qf[kc], acc);
            }
            s[mt] = acc;
        }
        __builtin_amdgcn_s_setprio(0);

        // ---- online softmax, per-lane state (q = col) ----
        float t[8];
        #pragma unroll
        for (int r = 0; r < 8; ++r)
            t[r] = fmaxf(fmaxf(s[0][r], s[0][r+8]), fmaxf(s[1][r], s[1][r+8]));
        float mx = fmaxf(fmaxf(fmaxf(t[0], t[1]), fmaxf(t[2], t[3])),
                         fmaxf(fmaxf(t[4], t[5]), fmaxf(t[6], t[7])));
        mx = fmaxf(mx, __shfl_xor(mx, 32));

        // defer-rescale: only rescale when tile max grows past m_i + 10
        if (__any(mx > m_i + 10.0f)) {
            float m_new = fmaxf(m_i, mx);
            float alpha = __builtin_amdgcn_exp2f(m_i - m_new);
            l_i *= alpha;
            #pragma unroll
            for (int nt = 0; nt < 3; ++nt)
                #pragma unroll
                for (int r = 0; r < 16; ++r) o[nt][r] *= alpha;
            m_i = m_new;
        }

        // p = exp2(s - m_i)  (bounded by 2^10; PV accum is f32)
        #pragma unroll
        for (int mt = 0; mt < 2; ++mt)
            #pragma unroll
            for (int r = 0; r < 16; ++r)
                s[mt][r] = __builtin_amdgcn_exp2f(s[mt][r] - m_i);

        // psum: depth-5 tree
        float a[8];
        #pragma unroll
        for (int r = 0; r < 8; ++r)
            a[r] = (s[0][r] + s[0][r+8]) + (s[1][r] + s[1][r+8]);
        float ps = ((a[0]+a[1]) + (a[2]+a[3])) + ((a[4]+a[5]) + (a[6]+a[7]));
        ps += __shfl_xor(ps, 32);
        l_i = l_i + ps;

        // ---- PV swapped: O^T[e][q] += V^T·P^T, P built in-register ----
        __builtin_amdgcn_s_setprio(1);                 // T5: favor MFMA wave
        #pragma unroll
        for (int kc = 0; kc < 4; ++kc) {
            const int mt = kc >> 1;
            const int g0 = (kc & 1) << 3;
            unsigned A0 = pk2(s[mt][g0+0], s[mt][g0+1]);
            unsigned A1 = pk2(s[mt][g0+2], s[mt][g0+3]);
            unsigned B0 = pk2(s[mt][g0+4], s[mt][g0+5]);
            unsigned B1 = pk2(s[mt][g0+6], s[mt][g0+7]);
            auto w0 = __builtin_amdgcn_permlane32_swap(A0, B0, false, false);
            auto w1 = __builtin_amdgcn_permlane32_swap(A1, B1, false, false);
            u32x4 pw;
            pw[0] = w0[0]; pw[1] = w1[0]; pw[2] = w0[1]; pw[3] = w1[1];
            f16x8 pb = __builtin_bit_cast(f16x8, pw);
            #pragma unroll
            for (int nt = 0; nt < 3; ++nt) {
                f16x8 va = *(const f16x8*)
                    &sKt[p][nt*32 + col][(((kc << 1) | half) ^ kswz) << 3];
                o[nt] = MFMA32H(va, pb, o[nt]);
            }
        }
        __builtin_amdgcn_s_setprio(0);
    }

    // ---- epilogue: NORMALIZED Ohat (fp16), lane owns row q = col ----
    float inv = 1.0f / l_i;
    unsigned short* Ob = (kh ? O1 : O0)
        + ((size_t)(b*S_DIM + q0 + w*32 + col))*E_DIM + h*D_DIM;
    #pragma unroll
    for (int nt = 0; nt < 3; ++nt)
        #pragma unroll
        for (int rg = 0; rg < 4; ++rg) {
            ushort4 pk;
            pk.x = f2h(o[nt][4*rg+0]*inv); pk.y = f2h(o[nt][4*rg+1]*inv);
            pk.z = f2h(o[nt][4*rg+2]*inv); pk.w = f2h(o[nt][4*rg+3]*inv);
            *(ushort4*)(Ob + nt*32 + 8*rg + 4*half) = pk;
        }
    if (lane < 32) {
        int q = q0 + w*32 + lane;
        ml[((size_t)(kh*B_DIM + b)*H_DIM + h)*S_DIM + q] = make_float2(m_i, l_i);
    }
}

// ---------------------------------------------------------------------------
// Merge scales from (m,l), log2 domain, NORMALIZED partials:
//   weight_j = l_j * 2^(m_j - mm);  s_j = weight_j * SCALE / sum(weight)
// ---------------------------------------------------------------------------
__device__ inline float2 mkscale(const float2* __restrict__ ml, int m, int h) {
    int b = m >> 11, q = m & (S_DIM - 1);
    float2 e0 = ml[((size_t)b*H_DIM + h)*S_DIM + q];
    float2 e1 = ml[((size_t)(B_DIM + b)*H_DIM + h)*S_DIM + q];
    float mm = fmaxf(e0.x, e1.x);
    float w0 = e0.y * __builtin_amdgcn_exp2f(e0.x - mm);
    float w1 = e1.y * __builtin_amdgcn_exp2f(e1.x - mm);
    float inv = SCALE_F / (w0 + w1);
    return make_float2(w0*inv, w1*inv);
}

// ---------------------------------------------------------------------------
// Output projection + fused 2-way partial-combine, BK=64, XCD swizzle.
// R24-proven minimal 2-phase pipeline: issue-early loads, use-late combine,
// one barrier per K-step.
// ---------------------------------------------------------------------------
__global__ __launch_bounds__(256) void gemm_out_kernel(
    const unsigned short* __restrict__ O0, const unsigned short* __restrict__ O1,
    const float2* __restrict__ ml, const unsigned short* __restrict__ Bt,
    const float* __restrict__ bo, float* __restrict__ out)
{
    __shared__ unsigned short sA[2*4096];   // [buf][panel][m][k32]
    __shared__ unsigned short sB[2*4096];

    const int tid  = threadIdx.x;
    const int lane = tid & 63;
    const int w    = tid >> 6;
    const int qn   = lane & 15, quad = lane >> 4;
    const int wm   = w & 1, wn = w >> 1;

    const int flat = blockIdx.x;            // 0..767
    const int g = flat & 7, s = flat >> 3;  // s: 0..95
    const int row0 = ((g << 3) + (s & 7)) << 6;   // 64 row-panels of 64
    const int col0 = (s >> 3) << 6;               // 12 col-tiles of 64

    const int ar = tid >> 2;            // 0..63
    const int ak = (tid & 3) << 3;      // 0,8,16,24

    const size_t r0o = (size_t)(row0 + ar)*E_DIM;
    const unsigned short* gB = Bt + (size_t)(col0 + ar)*E_DIM + ak;

    f32x4 acc[2][2];
    #pragma unroll
    for (int mt = 0; mt < 2; ++mt)
        #pragma unroll
        for (int nt = 0; nt < 2; ++nt)
            { acc[mt][nt][0]=0.f; acc[mt][nt][1]=0.f; acc[mt][nt][2]=0.f; acc[mt][nt][3]=0.f; }

    // tile-0 combine inputs + scales
    f16x8 uA = *(const f16x8*)(O0 + r0o + ak);
    f16x8 vA = *(const f16x8*)(O1 + r0o + ak);
    f16x8 uB = *(const f16x8*)(O0 + r0o + 32 + ak);
    f16x8 vB = *(const f16x8*)(O1 + r0o + 32 + ak);
    int hA = 0, hB = 0;                    // heads of panels (k<96 -> both 0)
    float2 s2 = mkscale(ml, row0 + ar, 0);
    _Float16 axA = (_Float16)s2.x, ayA = (_Float16)s2.y;
    _Float16 axB = axA, ayB = ayA;

    // prologue: stage tile 0 into buf 0
    {
        f16x8 c0 = uA * axA + vA * ayA;
        f16x8 c1 = uB * axB + vB * ayB;
        *(f16x8*)&sA[       ar*32 + ak] = c0;
        *(f16x8*)&sA[2048 + ar*32 + ak] = c1;
        gload16(gB,      sB + tid*8);
        gload16(gB + 32, sB + 2048 + tid*8);
    }
    __syncthreads();

    for (int it = 0; it < 12; ++it) {
        const int cur = it & 1, nb = cur ^ 1;
        const bool hasNext = it < 11;
        const int kn = (it + 1) << 6;

        if (hasNext) {                      // issue-early: next-tile loads
            gload16(gB + kn,      sB + nb*4096 + tid*8);
            gload16(gB + kn + 32, sB + nb*4096 + 2048 + tid*8);
            uA = *(const f16x8*)(O0 + r0o + kn + ak);
            vA = *(const f16x8*)(O1 + r0o + kn + ak);
            uB = *(const f16x8*)(O0 + r0o + kn + 32 + ak);
            vB = *(const f16x8*)(O1 + r0o + kn + 32 + ak);
        }

        #pragma unroll
        for (int kk = 0; kk < 2; ++kk) {
            f16x8 af[2], bf[2];
            #pragma unroll
            for (int mt = 0; mt < 2; ++mt)
                af[mt] = *(const f16x8*)
                    &sA[cur*4096 + kk*2048 + (wm*32 + mt*16 + qn)*32 + quad*8];
            #pragma unroll
            for (int nt = 0; nt < 2; ++nt)
                bf[nt] = *(const f16x8*)
                    &sB[cur*4096 + kk*2048 + (wn*32 + nt*16 + qn)*32 + quad*8];
            #pragma unroll
            for (int mt = 0; mt < 2; ++mt)
                #pragma unroll
                for (int nt = 0; nt < 2; ++nt)
                    acc[mt][nt] = MFMA16H(af[mt], bf[nt], acc[mt][nt]);
        }

        if (hasNext) {                      // use-late: combine + sA write
            int nhA = kn / D_DIM, nhB = (kn + 32) / D_DIM;
            if (nhA != hA) {
                float2 t = mkscale(ml, row0 + ar, nhA);
                axA = (_Float16)t.x; ayA = (_Float16)t.y; hA = nhA;
            }
            if (nhB != hB) {
                float2 t = mkscale(ml, row0 + ar, nhB);
                axB = (_Float16)t.x; ayB = (_Float16)t.y; hB = nhB;
            }
            f16x8 c0 = uA * axA + vA * ayA;
            f16x8 c1 = uB * axB + vB * ayB;
            *(f16x8*)&sA[nb*4096 +        ar*32 + ak] = c0;
            *(f16x8*)&sA[nb*4096 + 2048 + ar*32 + ak] = c1;
        }
        __syncthreads();   // drains gload16 (vmcnt) + ds ops (lgkm)
    }

    #pragma unroll
    for (int nt = 0; nt < 2; ++nt) {
        int n = col0 + wn*32 + nt*16 + qn;
        float bias = bo[n];
        #pragma unroll
        for (int mt = 0; mt < 2; ++mt)
            #pragma unroll
            for (int r = 0; r < 4; ++r) {
                int m = row0 + wm*32 + mt*16 + quad*4 + r;
                out[(size_t)m*E_DIM + n] = acc[mt][nt][r] + bias;
            }
    }
}

// ---------------------------------------------------------------------------
extern "C" void kernel_launch(void* const* d_in, const int* in_sizes, int n_in,
                              void* d_out, int out_size, void* d_ws, size_t ws_size,
                              hipStream_t stream)
{
    const float* x  = (const float*)d_in[0];
    const float* Wq = (const float*)d_in[1];
    const float* bq = (const float*)d_in[2];
    const float* Wk = (const float*)d_in[3];
    const float* bk = (const float*)d_in[4];
    const float* Wo = (const float*)d_in[5];
    const float* bo = (const float*)d_in[6];
    float* out = (float*)d_out;

    const size_t NE = (size_t)M_DIM * E_DIM;        // 3.1M elems
    const size_t WE = (size_t)E_DIM * E_DIM;        // 590K elems
    unsigned short* xf    = (unsigned short*)d_ws;  // NE (aliased Oh0 later)
    unsigned short* WqkT  = xf + NE;                // 2*WE  [Wq^T | Wk^T] fp16
    unsigned short* WoT   = WqkT + 2*WE;            // WE
    unsigned short* Qf    = WoT + WE;               // NE
    unsigned short* Kf    = Qf + NE;                // NE
    unsigned short* Oh1   = Kf + NE;                // NE
    float2*         mlbuf = (float2*)(Oh1 + NE);    // 2*B*H*S float2 = 512 KB
    unsigned short* Oh0   = xf;                     // alias: x dead after gemm_qk

    dim3 blk(256);
    hipLaunchKernelGGL(prep_kernel, dim3(3504), blk, 0, stream,
                       x, Wq, Wk, Wo, xf, WqkT, WqkT + WE, WoT);

    hipLaunchKernelGGL(gemm_qk_kernel, dim3(384), blk, 0, stream,
                       xf, WqkT, bq, bk, Qf, Kf);

    hipLaunchKernelGGL(attn_mfma_kernel, dim3(S_DIM/128, H_DIM, B_DIM*2), blk, 0,
                       stream, Qf, Kf, Oh0, Oh1, mlbuf);

    hipLaunchKernelGGL(gemm_out_kernel, dim3(768), blk, 0, stream,
                       Oh0, Oh1, mlbuf, WoT, bo, out);
}